// Round 2
// baseline (254.908 us; speedup 1.0000x reference)
//
#include <hip/hip_runtime.h>
#include <hip/hip_fp16.h>
#include <cfloat>

// NearestNeighborGraph: S=16, N=2048, D=64, K=16.
// Round-10 (resubmit; prior run died to container-acquisition infra failure).
// Occupancy restructure of the round-9 MFMA-filtered exact KNN:
//  - 32-row blocks (1024 blocks = 4/CU) instead of 64-row (512 = 2/CU).
//  - LDS 68.6KB -> 30.1KB: md/mi merge buffers alias the (dead-after-pass-1)
//    scoreboard; pbufi deleted (pass-1 indices were never consumed -> the
//    approx top-16 is value-only, which also cuts insert cost ~40%).
//  - Serial jj scoreboard loop split 2 lanes/row (8 iters instead of 16);
//    the extra list-merge level is an intra-wave __shfl. Tournament property
//    keeps the merged 16th (and tau) bit-identical to round-9, so pass-2
//    counts, RCAP risk, and the exact fp32 rescue output are unchanged.
//  Target: 2->4 blocks/CU (Occupancy 21%->~40%), latency-bound sections
//  overlap across 4 waves/SIMD.

typedef _Float16 half8 __attribute__((ext_vector_type(8)));
typedef float    f32x4 __attribute__((ext_vector_type(4)));

constexpr int NS = 16, NP = 2048, ND = 64, KK = 16;
constexpr int NWV = 4;              // waves per block
constexpr int NT  = NWV * 64;       // 256 threads
constexpr int RB  = 32;             // rows (i) per block
constexpr int ITN = RB / 16;        // 2 i-tiles
constexpr int JW  = NP / NWV;       // 512 j per wave
constexpr int NJT = JW / 16;        // 32 j-tiles per wave
constexpr int BUF = 8;              // approx push slots per lane
constexpr int MS  = 17;             // merge-tree stride
constexpr int SCB = 36;             // scoreboard stride ([j][i(32)+pad])
constexpr int RCAP = 32;            // candidate ring slots per row
constexpr float MARGIN = 1.0f;

// ---- prep: x2 (rotated chain, exact round-1 j-side value) + f16 copy ----
__global__ void prep_kernel(const float* __restrict__ h, float* __restrict__ x2,
                            _Float16* __restrict__ hh)
{
    int g = blockIdx.x * 256 + threadIdx.x;          // global row 0..NS*NP-1
    const float4* row = (const float4*)(h + (size_t)g * ND);
    int ph = g & 15;
    float a0 = 0.f, a1 = 0.f, a2 = 0.f, a3 = 0.f;
    #pragma unroll
    for (int k = 0; k < 16; ++k) {
        float4 v = row[(k + ph) & 15];
        a0 = fmaf(v.x, v.x, a0); a1 = fmaf(v.y, v.y, a1);
        a2 = fmaf(v.z, v.z, a2); a3 = fmaf(v.w, v.w, a3);
    }
    x2[g] = (a0 + a1) + (a2 + a3);
    _Float16* dst = hh + (size_t)g * ND;
    #pragma unroll
    for (int k = 0; k < 8; ++k) {
        float4 v0 = row[2 * k], v1 = row[2 * k + 1];
        half8 p;
        p[0] = (_Float16)v0.x; p[1] = (_Float16)v0.y;
        p[2] = (_Float16)v0.z; p[3] = (_Float16)v0.w;
        p[4] = (_Float16)v1.x; p[5] = (_Float16)v1.y;
        p[6] = (_Float16)v1.z; p[7] = (_Float16)v1.w;
        *(half8*)(dst + k * 8) = p;
    }
}

// value-only insert (approx path: only the 16th VALUE matters; idx unused)
__device__ __forceinline__ void insert16v(float (&d)[KK], float v)
{
    #pragma unroll
    for (int p = KK - 1; p > 0; --p) {
        bool sh = v < d[p - 1];
        bool he = v < d[p];
        d[p] = sh ? d[p - 1] : (he ? v : d[p]);
    }
    if (v < d[0]) d[0] = v;
}

// lexicographic (d2, j) insert == top_k tie-break (lowest index on equal d2)
__device__ __forceinline__ bool lexlt(float a, int ja, float b, int jb)
{
    return (a < b) || (a == b && ja < jb);
}
__device__ __forceinline__ void insert16x(float (&d)[KK], int (&ix)[KK],
                                          float v, int j)
{
    #pragma unroll
    for (int p = KK - 1; p > 0; --p) {
        bool sh = lexlt(v, j, d[p - 1], ix[p - 1]);
        bool he = lexlt(v, j, d[p], ix[p]);
        float nd = sh ? d[p - 1] : (he ? v : d[p]);
        int   ni = sh ? ix[p - 1] : (he ? j : ix[p]);
        d[p] = nd; ix[p] = ni;
    }
    if (lexlt(v, j, d[0], ix[0])) { d[0] = v; ix[0] = j; }
}

__global__ __launch_bounds__(NT, 4)
void knn_mfma(const float* __restrict__ h, const _Float16* __restrict__ hh,
              const float* __restrict__ x2g, float* __restrict__ out)
{
    // 7520 floats = 30080 B -> 4 blocks/CU (VGPR-capped; LDS allows 5)
    __shared__ __align__(16) float smem[7520];
    float* ldsx2  = smem;                    // [0,2048)
    float* scb    = smem + 2048;             // [2048,4352)  4 waves x 16 x 36
    float* pbufd  = smem + 4352;             // [4352,6400)  BUF x 256
    float* ldsthr = smem + 6400;             // [6400,6432)
    int*   ring   = (int*)(smem + 6432);     // [6432,7488)  32 x 33
    int*   rcnt   = (int*)(smem + 7488);     // [7488,7520)
    // aliases: scb is dead after pass 1, merge buffers live there
    float* md     = scb;                     // 2 x 32 x 17 = 1088 floats
    int*   mi     = (int*)(scb + 1088);      // 1088 ints

    const int t   = threadIdx.x;
    const int ln  = t & 63;
    const int qd  = ln >> 4;                 // quad within wave
    const int cl  = ln & 15;                 // col within quad group
    const int q   = t >> 6;                  // wave id (j-quarter)
    const int row = ln & 31;                 // lane's scoreboard row
    const int jh  = ln >> 5;                 // jj half (0/1)
    const int s   = blockIdx.x >> 6;
    const int rb  = blockIdx.x & 63;
    const int rowbase = rb * RB;             // block's 32 i-rows (sample-local)
    const float*    __restrict__ hs  = h  + (size_t)s * NP * ND;
    const _Float16* __restrict__ hhs = hh + (size_t)s * NP * ND;

    // stage sample x2; init thr + ring counts
    ((float4*)ldsx2)[t]       = ((const float4*)(x2g + s * NP))[t];
    ((float4*)ldsx2)[t + 256] = ((const float4*)(x2g + s * NP))[t + 256];
    if (t < RB) { ldsthr[t] = FLT_MAX; rcnt[t] = 0; }

    // A-frags: 2 i-tiles x 2 K-chunks; lane holds A[m=cl][k=qd*8..+7]
    half8 afr[ITN][2];
    #pragma unroll
    for (int it = 0; it < ITN; ++it) {
        const _Float16* ap = hhs + (size_t)(rowbase + it * 16 + cl) * ND + qd * 8;
        afr[it][0] = *(const half8*)(ap);
        afr[it][1] = *(const half8*)(ap + 32);
    }
    __syncthreads();

    // x2i (approx side, rotated values fine) for lane's 8 (it,r) rows
    float x2r[ITN * 4];
    #pragma unroll
    for (int it = 0; it < ITN; ++it)
        #pragma unroll
        for (int r = 0; r < 4; ++r)
            x2r[it * 4 + r] = ldsx2[rowbase + it * 16 + qd * 4 + r];

    float dist[KK]; int idx[KK];
    #pragma unroll
    for (int k = 0; k < KK; ++k) dist[k] = FLT_MAX;

    const int jbase = q * JW;
    float* scbW = scb + q * (16 * SCB);

    int cnt = 0;
    auto drain = [&]() {
        #pragma unroll 1
        for (int k = 0; k < BUF; ++k) {
            if (!__any(k < cnt)) break;
            bool  act = k < cnt;
            float dd  = pbufd[k * NT + t];
            insert16v(dist, act ? dd : FLT_MAX);
        }
        cnt = 0;
        ldsthr[row] = fminf(ldsthr[row], dist[KK - 1]);   // benign min-race
    };

    // ================= pass 1: MFMA scan + approx top-16 =================
    for (int jt = 0; jt < NJT; ++jt) {
        const int j0 = jbase + jt * 16;
        const _Float16* bp = hhs + (size_t)(j0 + cl) * ND + qd * 8;
        half8 blo = *(const half8*)(bp);
        half8 bhi = *(const half8*)(bp + 32);
        float x2j = ldsx2[j0 + cl];

        f32x4 acc[ITN];
        #pragma unroll
        for (int it = 0; it < ITN; ++it) {
            acc[it] = __builtin_amdgcn_mfma_f32_16x16x32_f16(
                          afr[it][0], blo, (f32x4){0.f, 0.f, 0.f, 0.f}, 0, 0, 0);
            acc[it] = __builtin_amdgcn_mfma_f32_16x16x32_f16(
                          afr[it][1], bhi, acc[it], 0, 0, 0);
        }
        // d2a -> scoreboard [j][i] (b128 per i-tile)
        #pragma unroll
        for (int it = 0; it < ITN; ++it) {
            f32x4 w;
            #pragma unroll
            for (int r = 0; r < 4; ++r)
                w[r] = fmaf(-2.f, acc[it][r], x2r[it * 4 + r] + x2j);
            *(f32x4*)(scbW + cl * SCB + it * 16 + qd * 4) = w;
        }
        // 2 lanes per row: lane handles its jj-half, push/drain
        float thrC = ldsthr[row];
        #pragma unroll
        for (int jj8 = 0; jj8 < 8; ++jj8) {
            int jj = jh * 8 + jj8;
            float d2 = scbW[jj * SCB + row];
            float lim = fminf(dist[KK - 1], thrC);
            pbufd[cnt * NT + t] = d2;
            cnt += (d2 < lim) ? 1 : 0;
            if (__any(cnt == BUF)) { drain(); thrC = ldsthr[row]; }
        }
    }
    drain();

    // ====== merge approx half-lists (shuffle + 2 LDS levels) -> tau =======
    __syncthreads();
    // level 0: upper half -> lower half within each wave
    #pragma unroll 1
    for (int k = 0; k < KK; ++k) {
        float v = __shfl(dist[k], row + 32);
        if (ln < 32) insert16v(dist, v);
    }
    #pragma unroll 1
    for (int lvl = 0; lvl < 2; ++lvl) {
        const int step = 1 << lvl;
        const int m    = (step << 1) - 1;
        const bool pub = ((q & m) == step) && ln < 32;
        const bool con = ((q & m) == 0) && ln < 32;
        const int reg  = q >> (lvl + 1);
        if (pub) {
            #pragma unroll
            for (int k = 0; k < KK; ++k)
                md[(reg * RB + row) * MS + k] = dist[k];
        }
        __syncthreads();
        if (con) {
            #pragma unroll 1
            for (int k = 0; k < KK; ++k)
                insert16v(dist, md[(reg * RB + row) * MS + k]);
        }
        __syncthreads();
    }
    if (q == 0 && ln < 32) ldsthr[row] = dist[KK - 1] + MARGIN;  // tau
    __syncthreads();

    // tau for lane's 8 rows into VGPRs
    float thrv[ITN * 4];
    #pragma unroll
    for (int it = 0; it < ITN; ++it)
        #pragma unroll
        for (int r = 0; r < 4; ++r)
            thrv[it * 4 + r] = ldsthr[it * 16 + qd * 4 + r];

    // ================= pass 2: re-scan, fill candidate rings ==============
    for (int jt = 0; jt < NJT; ++jt) {
        const int j0 = jbase + jt * 16;
        const _Float16* bp = hhs + (size_t)(j0 + cl) * ND + qd * 8;
        half8 blo = *(const half8*)(bp);
        half8 bhi = *(const half8*)(bp + 32);
        float x2j = ldsx2[j0 + cl];

        f32x4 acc[ITN];
        #pragma unroll
        for (int it = 0; it < ITN; ++it) {
            acc[it] = __builtin_amdgcn_mfma_f32_16x16x32_f16(
                          afr[it][0], blo, (f32x4){0.f, 0.f, 0.f, 0.f}, 0, 0, 0);
            acc[it] = __builtin_amdgcn_mfma_f32_16x16x32_f16(
                          afr[it][1], bhi, acc[it], 0, 0, 0);
        }
        #pragma unroll
        for (int it = 0; it < ITN; ++it) {
            #pragma unroll
            for (int r = 0; r < 4; ++r) {
                float d2 = fmaf(-2.f, acc[it][r], x2r[it * 4 + r] + x2j);
                if (d2 < thrv[it * 4 + r]) {
                    int rw = it * 16 + qd * 4 + r;
                    int slot = atomicAdd(&rcnt[rw], 1);
                    if (slot < RCAP) ring[rw * 33 + slot] = j0 + cl;
                }
            }
        }
    }
    __syncthreads();

    // ========== rescue: exact fp32 recompute of candidates ===============
    // row = ln&31; 8 workers per row: (wave q, half jh) take slots w8, w8+8, ...
    const int myrow = rowbase + row;
    float4 A[16];
    {
        const float4* ra = (const float4*)(hs + (size_t)myrow * ND);
        #pragma unroll
        for (int k = 0; k < 16; ++k) A[k] = ra[k];
    }
    float x2i;   // ascending chain (exact round-1 i-side value)
    {
        float a0 = 0.f, a1 = 0.f, a2 = 0.f, a3 = 0.f;
        #pragma unroll
        for (int k = 0; k < 16; ++k) {
            a0 = fmaf(A[k].x, A[k].x, a0); a1 = fmaf(A[k].y, A[k].y, a1);
            a2 = fmaf(A[k].z, A[k].z, a2); a3 = fmaf(A[k].w, A[k].w, a3);
        }
        x2i = (a0 + a1) + (a2 + a3);
    }
    #pragma unroll
    for (int k = 0; k < KK; ++k) { dist[k] = FLT_MAX; idx[k] = 0; }

    const int cntR = min(rcnt[row], RCAP);
    const int w8 = q * 2 + jh;
    #pragma unroll 1
    for (int k = w8; k < cntR; k += 8) {
        int j = ring[row * 33 + k];
        const float4* cv = (const float4*)(hs + (size_t)j * ND);
        float a0 = 0.f, a1 = 0.f, a2 = 0.f, a3 = 0.f;
        #pragma unroll
        for (int kk = 0; kk < 16; ++kk) {
            float4 c = cv[kk];
            a0 = fmaf(A[kk].x, c.x, a0); a1 = fmaf(A[kk].y, c.y, a1);
            a2 = fmaf(A[kk].z, c.z, a2); a3 = fmaf(A[kk].w, c.w, a3);
        }
        float dotv = (a0 + a1) + (a2 + a3);
        float d2 = fmaf(-2.0f, dotv, x2i + ldsx2[j]);
        insert16x(dist, idx, d2, j);
    }

    // ---- final exact merge (lex): shuffle level + 2 LDS levels ----
    #pragma unroll 1
    for (int k = 0; k < KK; ++k) {
        float v  = __shfl(dist[k], row + 32);
        int   jv = __shfl(idx[k],  row + 32);
        if (ln < 32) insert16x(dist, idx, v, jv);
    }
    __syncthreads();
    #pragma unroll 1
    for (int lvl = 0; lvl < 2; ++lvl) {
        const int step = 1 << lvl;
        const int m    = (step << 1) - 1;
        const bool pub = ((q & m) == step) && ln < 32;
        const bool con = ((q & m) == 0) && ln < 32;
        const int reg  = q >> (lvl + 1);
        if (pub) {
            #pragma unroll
            for (int k = 0; k < KK; ++k) {
                md[(reg * RB + row) * MS + k] = dist[k];
                mi[(reg * RB + row) * MS + k] = idx[k];
            }
        }
        __syncthreads();
        if (con) {
            #pragma unroll 1
            for (int k = 0; k < KK; ++k)
                insert16x(dist, idx, md[(reg * RB + row) * MS + k],
                                     mi[(reg * RB + row) * MS + k]);
        }
        __syncthreads();
    }

    // ---- output (wave 0, lower half) ----
    if (q == 0 && ln < 32) {
        const int off = s * NP;
        const size_t rg = (size_t)off + myrow;
        float* o0 = out + rg * KK;
        float* o1 = out + (size_t)NS * NP * KK + rg * KK;
        float* o2 = out + (size_t)2 * NS * NP * KK + rg * KK;
        #pragma unroll
        for (int k = 0; k < KK; ++k) o0[k] = dist[k];
        #pragma unroll
        for (int k = 0; k < KK; ++k) o1[k] = (float)(idx[k] + off);
        #pragma unroll
        for (int k = 0; k < KK; ++k) o2[k] = (float)(off + myrow);
    }
}

extern "C" void kernel_launch(void* const* d_in, const int* in_sizes, int n_in,
                              void* d_out, int out_size, void* d_ws, size_t ws_size,
                              hipStream_t stream)
{
    const float* h = (const float*)d_in[0];
    float* out = (float*)d_out;
    float*    x2 = (float*)d_ws;                     // 32768 floats (128 KB)
    _Float16* hh = (_Float16*)(x2 + NS * NP);        // 16*2048*64 halves (4 MB)

    hipLaunchKernelGGL(prep_kernel, dim3(NS * NP / 256), dim3(256), 0, stream,
                       h, x2, hh);
    hipLaunchKernelGGL(knn_mfma, dim3(NS * (NP / RB)), dim3(NT), 0, stream,
                       h, hh, x2, out);
}

// Round 3
// 216.711 us; speedup vs baseline: 1.1763x; 1.1763x over previous
//
#include <hip/hip_runtime.h>
#include <hip/hip_fp16.h>
#include <cfloat>

// NearestNeighborGraph: S=16, N=2048, D=64, K=16.
// Round-11: work-deletion rewrite of the tau estimator.
//  Round-10 post-mortem: doubling occupancy (21->40%) left duration flat ->
//  kernel is VALU/LDS instruction-bound, not latency-bound. The approx
//  top-16 machinery (pbuf pushes, votes, 48-op insert chains, merge trees)
//  existed only to derive tau. Replaced by:
//   Stage A: MFMA scan; per (row, wave) substream of 512 j's keep the exact
//     top-4 of approx d2' = x2j - 2*dot_f16 (4 ops/elem via fmed3).
//     Union of 4 substream top-4s = 16 elements <= M = max(4ths)
//     -> row's approx 16th <= M -> tau = M + MARGIN keeps all true top-16
//     (fp32-exact x2j, f16 dot err ~0.16 -> 3x margin).
//   Stage B: re-scan with MFMA, filter d2' < tau into per-row rings
//     (RCAP=128: overflow prob ~1e-7 over all rows; E[survivors] ~25).
//   Rescue: exact fp32 recompute (bit-identical round-1 chains) + lex
//     top-16 -> output identical to rounds 1-10.
//  Final merges gated with early-break (sorted incoming -> monotone exit).

typedef _Float16 half8 __attribute__((ext_vector_type(8)));
typedef float    f32x4 __attribute__((ext_vector_type(4)));

constexpr int NS = 16, NP = 2048, ND = 64, KK = 16;
constexpr int NWV = 4;              // waves per block
constexpr int NT  = NWV * 64;       // 256 threads
constexpr int RB  = 32;             // rows (i) per block
constexpr int ITN = RB / 16;        // 2 i-tiles
constexpr int JW  = NP / NWV;       // 512 j per wave
constexpr int NJT = JW / 16;        // 32 j-tiles per wave
constexpr int MS  = 17;             // merge-tree stride
constexpr int SCB = 36;             // scoreboard stride ([j][i(32)+pad])
constexpr int RCAP = 128;           // candidate ring slots per row
constexpr int RSTR = RCAP + 1;      // ring stride
constexpr float MARGIN = 1.0f;

// ---- prep: x2 (rotated chain, exact round-1 j-side value) + f16 copy ----
__global__ void prep_kernel(const float* __restrict__ h, float* __restrict__ x2,
                            _Float16* __restrict__ hh)
{
    int g = blockIdx.x * 128 + threadIdx.x;          // global row 0..NS*NP-1
    const float4* row = (const float4*)(h + (size_t)g * ND);
    int ph = g & 15;
    float a0 = 0.f, a1 = 0.f, a2 = 0.f, a3 = 0.f;
    #pragma unroll
    for (int k = 0; k < 16; ++k) {
        float4 v = row[(k + ph) & 15];
        a0 = fmaf(v.x, v.x, a0); a1 = fmaf(v.y, v.y, a1);
        a2 = fmaf(v.z, v.z, a2); a3 = fmaf(v.w, v.w, a3);
    }
    x2[g] = (a0 + a1) + (a2 + a3);
    _Float16* dst = hh + (size_t)g * ND;
    #pragma unroll
    for (int k = 0; k < 8; ++k) {
        float4 v0 = row[2 * k], v1 = row[2 * k + 1];
        half8 p;
        p[0] = (_Float16)v0.x; p[1] = (_Float16)v0.y;
        p[2] = (_Float16)v0.z; p[3] = (_Float16)v0.w;
        p[4] = (_Float16)v1.x; p[5] = (_Float16)v1.y;
        p[6] = (_Float16)v1.z; p[7] = (_Float16)v1.w;
        *(half8*)(dst + k * 8) = p;
    }
}

// lexicographic (d2, j) insert == top_k tie-break (lowest index on equal d2)
__device__ __forceinline__ bool lexlt(float a, int ja, float b, int jb)
{
    return (a < b) || (a == b && ja < jb);
}
__device__ __forceinline__ void insert16x(float (&d)[KK], int (&ix)[KK],
                                          float v, int j)
{
    #pragma unroll
    for (int p = KK - 1; p > 0; --p) {
        bool sh = lexlt(v, j, d[p - 1], ix[p - 1]);
        bool he = lexlt(v, j, d[p], ix[p]);
        float nd = sh ? d[p - 1] : (he ? v : d[p]);
        int   ni = sh ? ix[p - 1] : (he ? j : ix[p]);
        d[p] = nd; ix[p] = ni;
    }
    if (lexlt(v, j, d[0], ix[0])) { d[0] = v; ix[0] = j; }
}

__global__ __launch_bounds__(NT, 4)
void knn_mfma(const float* __restrict__ h, const _Float16* __restrict__ hh,
              const float* __restrict__ x2g, float* __restrict__ out)
{
    // 8672 floats = 34688 B -> 4 blocks/CU
    __shared__ __align__(16) float smem[8672];
    float* ldsx2  = smem;                    // [0,2048)
    float* scb    = smem + 2048;             // [2048,4352)  4 waves x 16 x 36
    float* mw     = smem + 4352;             // [4352,4480)  4 waves x 32 rows
    float* ldsthr = smem + 4480;             // [4480,4512)
    int*   ring   = (int*)(smem + 4512);     // [4512,8640)  32 x 129
    int*   rcnt   = (int*)(smem + 8640);     // [8640,8672)
    // aliases: scb is dead after stage A; final-merge buffers live there
    float* md     = scb;                     // 2 x 32 x 17 = 1088 floats
    int*   mi     = (int*)(scb + 1088);      // 1088 ints

    const int t   = threadIdx.x;
    const int ln  = t & 63;
    const int qd  = ln >> 4;                 // quad within wave
    const int cl  = ln & 15;                 // col within quad group
    const int q   = t >> 6;                  // wave id (j-quarter)
    const int row = ln & 31;                 // lane's scoreboard row
    const int jh  = ln >> 5;                 // jj half (0/1)
    const int s   = blockIdx.x >> 6;
    const int rb  = blockIdx.x & 63;
    const int rowbase = rb * RB;             // block's 32 i-rows (sample-local)
    const float*    __restrict__ hs  = h  + (size_t)s * NP * ND;
    const _Float16* __restrict__ hhs = hh + (size_t)s * NP * ND;

    // stage sample x2; init ring counts
    ((float4*)ldsx2)[t]       = ((const float4*)(x2g + s * NP))[t];
    ((float4*)ldsx2)[t + 256] = ((const float4*)(x2g + s * NP))[t + 256];
    if (t < RB) rcnt[t] = 0;

    // A-frags: 2 i-tiles x 2 K-chunks; lane holds A[m=cl][k=qd*8..+7]
    half8 afr[ITN][2];
    #pragma unroll
    for (int it = 0; it < ITN; ++it) {
        const _Float16* ap = hhs + (size_t)(rowbase + it * 16 + cl) * ND + qd * 8;
        afr[it][0] = *(const half8*)(ap);
        afr[it][1] = *(const half8*)(ap + 32);
    }
    __syncthreads();

    const int jbase = q * JW;
    float* scbW = scb + q * (16 * SCB);

    // ========= stage A: MFMA scan, per-(row, wave-half) top-4 of d2' =========
    // d2' = x2j - 2*dot  (x2i dropped: per-row constant, rank-invariant)
    float s1 = FLT_MAX, s2 = FLT_MAX, s3 = FLT_MAX, s4 = FLT_MAX;
    const int jro = jh * 8;
    for (int jt = 0; jt < NJT; ++jt) {
        const int j0 = jbase + jt * 16;
        const _Float16* bp = hhs + (size_t)(j0 + cl) * ND + qd * 8;
        half8 blo = *(const half8*)(bp);
        half8 bhi = *(const half8*)(bp + 32);
        float x2j = ldsx2[j0 + cl];

        f32x4 acc[ITN];
        #pragma unroll
        for (int it = 0; it < ITN; ++it) {
            acc[it] = __builtin_amdgcn_mfma_f32_16x16x32_f16(
                          afr[it][0], blo, (f32x4){0.f, 0.f, 0.f, 0.f}, 0, 0, 0);
            acc[it] = __builtin_amdgcn_mfma_f32_16x16x32_f16(
                          afr[it][1], bhi, acc[it], 0, 0, 0);
        }
        // d2' -> scoreboard [j][i] (b128 per i-tile)
        #pragma unroll
        for (int it = 0; it < ITN; ++it) {
            f32x4 w;
            #pragma unroll
            for (int r = 0; r < 4; ++r)
                w[r] = fmaf(-2.f, acc[it][r], x2j);
            *(f32x4*)(scbW + cl * SCB + it * 16 + qd * 4) = w;
        }
        // lane = (row, jh): fold its 8 values into sorted top-4 registers
        #pragma unroll
        for (int u = 0; u < 8; ++u) {
            float v  = scbW[(jro + u) * SCB + row];
            float n1 = fminf(s1, v);
            float n2 = __builtin_amdgcn_fmed3f(s1, s2, v);
            float n3 = __builtin_amdgcn_fmed3f(s2, s3, v);
            float n4 = __builtin_amdgcn_fmed3f(s3, s4, v);
            s1 = n1; s2 = n2; s3 = n3; s4 = n4;
        }
    }
    // merge the two jh-half top-4s (bitonic half-clean) -> exact wave top-4 max
    {
        float o1 = __shfl(s1, row + 32);
        float o2 = __shfl(s2, row + 32);
        float o3 = __shfl(s3, row + 32);
        float o4 = __shfl(s4, row + 32);
        if (ln < 32) {
            float m1 = fminf(s1, o4), m2 = fminf(s2, o3);
            float m3 = fminf(s3, o2), m4 = fminf(s4, o1);
            mw[q * 32 + row] = fmaxf(fmaxf(m1, m2), fmaxf(m3, m4));
        }
    }
    __syncthreads();
    // tau = max over 4 waves of (exact 4th of 512-substream) + margin
    if (q == 0 && ln < 32) {
        float m0 = mw[row], m1 = mw[32 + row];
        float m2 = mw[64 + row], m3 = mw[96 + row];
        ldsthr[row] = fmaxf(fmaxf(m0, m1), fmaxf(m2, m3)) + MARGIN;
    }
    __syncthreads();

    // tau for lane's 8 rows into VGPRs
    float thrv[ITN * 4];
    #pragma unroll
    for (int it = 0; it < ITN; ++it)
        #pragma unroll
        for (int r = 0; r < 4; ++r)
            thrv[it * 4 + r] = ldsthr[it * 16 + qd * 4 + r];

    // ========= stage B: re-scan, filter d2' < tau into candidate rings =======
    for (int jt = 0; jt < NJT; ++jt) {
        const int j0 = jbase + jt * 16;
        const _Float16* bp = hhs + (size_t)(j0 + cl) * ND + qd * 8;
        half8 blo = *(const half8*)(bp);
        half8 bhi = *(const half8*)(bp + 32);
        float x2j = ldsx2[j0 + cl];

        f32x4 acc[ITN];
        #pragma unroll
        for (int it = 0; it < ITN; ++it) {
            acc[it] = __builtin_amdgcn_mfma_f32_16x16x32_f16(
                          afr[it][0], blo, (f32x4){0.f, 0.f, 0.f, 0.f}, 0, 0, 0);
            acc[it] = __builtin_amdgcn_mfma_f32_16x16x32_f16(
                          afr[it][1], bhi, acc[it], 0, 0, 0);
        }
        #pragma unroll
        for (int it = 0; it < ITN; ++it) {
            #pragma unroll
            for (int r = 0; r < 4; ++r) {
                float d2 = fmaf(-2.f, acc[it][r], x2j);
                if (d2 < thrv[it * 4 + r]) {
                    int rw = it * 16 + qd * 4 + r;
                    int slot = atomicAdd(&rcnt[rw], 1);
                    if (slot < RCAP) ring[rw * RSTR + slot] = j0 + cl;
                }
            }
        }
    }
    __syncthreads();

    // ========== rescue: exact fp32 recompute of candidates ===============
    // row = ln&31; 8 workers per row: (wave q, half jh) take slots w8, w8+8,...
    const int myrow = rowbase + row;
    float4 A[16];
    {
        const float4* ra = (const float4*)(hs + (size_t)myrow * ND);
        #pragma unroll
        for (int k = 0; k < 16; ++k) A[k] = ra[k];
    }
    float x2i;   // ascending chain (exact round-1 i-side value)
    {
        float a0 = 0.f, a1 = 0.f, a2 = 0.f, a3 = 0.f;
        #pragma unroll
        for (int k = 0; k < 16; ++k) {
            a0 = fmaf(A[k].x, A[k].x, a0); a1 = fmaf(A[k].y, A[k].y, a1);
            a2 = fmaf(A[k].z, A[k].z, a2); a3 = fmaf(A[k].w, A[k].w, a3);
        }
        x2i = (a0 + a1) + (a2 + a3);
    }
    float dist[KK]; int idx[KK];
    #pragma unroll
    for (int k = 0; k < KK; ++k) { dist[k] = FLT_MAX; idx[k] = 0; }

    const int cntR = min(rcnt[row], RCAP);
    const int w8 = q * 2 + jh;
    #pragma unroll 1
    for (int k = w8; k < cntR; k += 8) {
        int j = ring[row * RSTR + k];
        const float4* cv = (const float4*)(hs + (size_t)j * ND);
        float a0 = 0.f, a1 = 0.f, a2 = 0.f, a3 = 0.f;
        #pragma unroll
        for (int kk = 0; kk < 16; ++kk) {
            float4 c = cv[kk];
            a0 = fmaf(A[kk].x, c.x, a0); a1 = fmaf(A[kk].y, c.y, a1);
            a2 = fmaf(A[kk].z, c.z, a2); a3 = fmaf(A[kk].w, c.w, a3);
        }
        float dotv = (a0 + a1) + (a2 + a3);
        float d2 = fmaf(-2.0f, dotv, x2i + ldsx2[j]);
        if (lexlt(d2, j, dist[KK - 1], idx[KK - 1]))
            insert16x(dist, idx, d2, j);
    }

    // ---- final exact merge (lex): shuffle level + 2 LDS levels (gated) ----
    #pragma unroll 1
    for (int k = 0; k < KK; ++k) {
        float v  = __shfl(dist[k], row + 32);
        int   jv = __shfl(idx[k],  row + 32);
        bool need = (ln < 32) && lexlt(v, jv, dist[KK - 1], idx[KK - 1]);
        if (!__any(need)) break;
        if (need) insert16x(dist, idx, v, jv);
    }
    __syncthreads();
    #pragma unroll 1
    for (int lvl = 0; lvl < 2; ++lvl) {
        const int step = 1 << lvl;
        const int m    = (step << 1) - 1;
        const bool pub = ((q & m) == step) && ln < 32;
        const int reg  = q >> (lvl + 1);
        if (pub) {
            #pragma unroll
            for (int k = 0; k < KK; ++k) {
                md[(reg * RB + row) * MS + k] = dist[k];
                mi[(reg * RB + row) * MS + k] = idx[k];
            }
        }
        __syncthreads();
        if ((q & m) == 0) {
            #pragma unroll 1
            for (int k = 0; k < KK; ++k) {
                float v  = md[(reg * RB + row) * MS + k];
                int   jv = mi[(reg * RB + row) * MS + k];
                bool need = (ln < 32) && lexlt(v, jv, dist[KK - 1], idx[KK - 1]);
                if (!__any(need)) break;
                if (need) insert16x(dist, idx, v, jv);
            }
        }
        __syncthreads();
    }

    // ---- output (wave 0, lower half) ----
    if (q == 0 && ln < 32) {
        const int off = s * NP;
        const size_t rg = (size_t)off + myrow;
        float* o0 = out + rg * KK;
        float* o1 = out + (size_t)NS * NP * KK + rg * KK;
        float* o2 = out + (size_t)2 * NS * NP * KK + rg * KK;
        #pragma unroll
        for (int k = 0; k < KK; ++k) o0[k] = dist[k];
        #pragma unroll
        for (int k = 0; k < KK; ++k) o1[k] = (float)(idx[k] + off);
        #pragma unroll
        for (int k = 0; k < KK; ++k) o2[k] = (float)(off + myrow);
    }
}

extern "C" void kernel_launch(void* const* d_in, const int* in_sizes, int n_in,
                              void* d_out, int out_size, void* d_ws, size_t ws_size,
                              hipStream_t stream)
{
    const float* h = (const float*)d_in[0];
    float* out = (float*)d_out;
    float*    x2 = (float*)d_ws;                     // 32768 floats (128 KB)
    _Float16* hh = (_Float16*)(x2 + NS * NP);        // 16*2048*64 halves (4 MB)

    hipLaunchKernelGGL(prep_kernel, dim3(NS * NP / 128), dim3(128), 0, stream,
                       h, x2, hh);
    hipLaunchKernelGGL(knn_mfma, dim3(NS * (NP / RB)), dim3(NT), 0, stream,
                       h, hh, x2, out);
}